// Round 7
// baseline (1051.321 us; speedup 1.0000x reference)
//
#include <hip/hip_runtime.h>
#include <hip/hip_bf16.h>

// Problem constants
#define PP 64
#define BB 256
#define HH 512
#define MM (PP * BB)          // 16384 fused batch rows

// d_out layout: out (B,P,H) | hn (P,2,B,H) | cn (P,2,B,H)
#define HN_BASE (BB * PP * HH)                 // 8388608
#define CN_BASE (HN_BASE + PP * 2 * BB * HH)   // 25165824

// ---- workspace layout (bytes): FRAGMENT-ORDER bf16 tile images ----
// 16 KB tile = 1024 slots of 16B, slot = (rb*2+ks)*64 + lane (lane=qd*16+lr):
//   A1A tiles (pb 0..127, kt 0..7): lane holds A[rb*16+lr][kt*64+ks*32+qd*8..+8]
//   W  tiles  (hb32 0..15, kt 0..7): rb=g*2+half -> row g*512+hb32*32+half*16+lr
#define TILE_BYTES 16384
#define WS_A1A  16777216ull                   // h_new0 image (written by L0)  16 MiB
#define WS_W0   50331648ull                   // whh0  image   2 MiB
#define WS_W1A  52428800ull                   // wih1  image   2 MiB
#define WS_W1B  54525952ull                   // whh1  image   2 MiB
#define WS_NEED 56623104ull

typedef __attribute__((ext_vector_type(8))) short bf16x8;
typedef __attribute__((ext_vector_type(4))) float floatx4;

__device__ __forceinline__ float sigf(float x) { return 1.0f / (1.0f + __expf(-x)); }
__device__ __forceinline__ float tanh_(float x) { return 2.0f / (1.0f + __expf(-2.0f * x)) - 1.0f; }

// float -> bf16 bits, round-nearest-even (finite inputs only)
__device__ __forceinline__ short f2bf(float f) {
  unsigned u = __float_as_uint(f);
  u = (u + 0x7FFFu + ((u >> 16) & 1u)) >> 16;
  return (short)u;
}

template <typename T>
__device__ __forceinline__ float tofl(T v);
template <> __device__ __forceinline__ float tofl<float>(float v) { return v; }
template <> __device__ __forceinline__ float tofl<__hip_bfloat16>(__hip_bfloat16 v) { return __bfloat162float(v); }

template <typename T>
__device__ __forceinline__ T fromfl(float v);
template <> __device__ __forceinline__ float fromfl<float>(float v) { return v; }
template <> __device__ __forceinline__ __hip_bfloat16 fromfl<__hip_bfloat16>(float v) { return __float2bfloat16(v); }

// load 8 consecutive elements as bf16x8 (16B-aligned for bf16, 32B for f32)
template <typename T>
__device__ __forceinline__ bf16x8 load8(const T* p);
template <> __device__ __forceinline__ bf16x8 load8<__hip_bfloat16>(const __hip_bfloat16* p) {
  return *(const bf16x8*)p;
}
template <> __device__ __forceinline__ bf16x8 load8<float>(const float* p) {
  float4 f0 = *(const float4*)p;
  float4 f1 = *((const float4*)p + 1);
  bf16x8 v;
  v[0] = f2bf(f0.x); v[1] = f2bf(f0.y); v[2] = f2bf(f0.z); v[3] = f2bf(f0.w);
  v[4] = f2bf(f1.x); v[5] = f2bf(f1.y); v[6] = f2bf(f1.z); v[7] = f2bf(f1.w);
  return v;
}

// fp32 vs bf16 buffer detection (see original kernel comment)
__device__ __forceinline__ bool detect_f32(const void* w_ih0) {
  const unsigned short* p = (const unsigned short*)w_ih0;
  int l = threadIdx.x & 63;
  unsigned short a = p[2 * l], b = p[2 * l + 1];
  int big = ((a & 0x7F80) >= 0x3F80) || ((b & 0x7F80) >= 0x3F80);
  return __any(big);
}

// ============================================================================
// Pre-pass: fragment-order bf16 W images. grid (48 = 3*16, 8 kt), block 256.
// ============================================================================
template <typename T>
__device__ __forceinline__ void prep_W_body(const T* __restrict__ w0, const T* __restrict__ w1a,
                                            const T* __restrict__ w1b, char* __restrict__ ws) {
  const int m = blockIdx.x >> 4, hb = blockIdx.x & 15, kt = blockIdx.y;
  const T* src = (m == 0) ? w0 : (m == 1 ? w1a : w1b);
  const size_t base = (m == 0) ? WS_W0 : (m == 1 ? WS_W1A : WS_W1B);
  char* dst = ws + base + ((size_t)(hb * 8 + kt)) * TILE_BYTES;
  const int tid = threadIdx.x;
#pragma unroll
  for (int i = 0; i < 4; ++i) {
    int idx = i * 256 + tid;
    int ln  = idx & 63;
    int ks  = (idx >> 6) & 1;
    int rb  = idx >> 7;               // rb = g*2 + half
    int g   = rb >> 1, half = rb & 1;
    int j   = g * 512 + hb * 32 + half * 16 + (ln & 15);   // row in [2048,512]
    int col = kt * 64 + ks * 32 + (ln >> 4) * 8;
    *(bf16x8*)(dst + (size_t)idx * 16) = load8<T>(src + (size_t)j * 512 + col);
  }
}

__global__ void __launch_bounds__(256) prep_W_k(const void* w0, const void* w1a, const void* w1b,
                                                const void* det, void* ws) {
  if (detect_f32(det)) prep_W_body<float>((const float*)w0, (const float*)w1a, (const float*)w1b, (char*)ws);
  else prep_W_body<__hip_bfloat16>((const __hip_bfloat16*)w0, (const __hip_bfloat16*)w1a,
                                   (const __hip_bfloat16*)w1b, (char*)ws);
}

// ============================================================================
// Panel kernel: block = 64 rows x all 512 h.  A panel (64 x K bf16) staged
// into LDS ONCE (fp32 converted inline; L1's first half from the A1A image),
// one __syncthreads, then a barrier-free compute loop:
//   for hb(8): for kt(K/64, unrolled): reg-dbuf W frags (static idx), 8
//   ds_read_b128 A frags, 32 MFMA; per-hb epilogue (cell + stores).
// No DMA, no raw barriers, no waitcnt builtins.
// ============================================================================
template <typename T, int LAYER>
__device__ __forceinline__ void lstm_panel_body(
    const T* __restrict__ xin, const T* __restrict__ h0, const T* __restrict__ c0,
    const T* __restrict__ wih, const T* __restrict__ bih, const T* __restrict__ bhh,
    T* __restrict__ out, char* __restrict__ ws, char* lds)
{
  const int tid  = threadIdx.x;
  const int blk  = blockIdx.x;       // 0..255, rows [blk*64, blk*64+64)
  const int lane = tid & 63;
  const int wid  = tid >> 6;
  const int quad = lane >> 4;
  const int lrow = lane & 15;

  const int ped   = blk >> 2;        // pedestrian (uniform per block)
  const int bbase = (blk & 3) * 64;  // batch-B base of this block's rows
  const int pb    = blk >> 1;        // A1A image tile row-block
  const int rrb   = (blk & 1) * 64;  // row offset inside the 128-row image tile

  constexpr int KITERS = (LAYER == 0) ? 8 : 16;   // K = 512 or 1024

  // ---- stage A panel into LDS (fragment order), once ----
  // lds byte = ((kt*4+rb)*2+ks)*1024 + lane*16 == chunk_idx*16
#pragma unroll
  for (int i = 0; i < KITERS * 2; ++i) {
    int idx = i * 256 + tid;          // chunk 0 .. KITERS*512-1
    int ln  = idx & 63;
    int ks  = (idx >> 6) & 1;
    int rb  = (idx >> 7) & 3;
    int kt  = idx >> 9;
    bf16x8 v;
    if (LAYER == 0) {
      int r   = rb * 16 + (ln & 15);
      int col = kt * 64 + ks * 32 + (ln >> 4) * 8;
      v = load8<T>(h0 + ((size_t)((ped * 2) * 256 + bbase + r)) * 512 + col);
    } else if (kt < 8) {
      // h_new0 from the bf16 A1A fragment image (written by layer 0)
      int rr = rrb + rb * 16 + (ln & 15);
      const char* src = ws + WS_A1A + ((size_t)(pb * 8 + kt)) * TILE_BYTES
          + ((size_t)(((rr >> 4) * 2 + ks) * 64 + (ln >> 4) * 16 + (rr & 15))) * 16;
      v = *(const bf16x8*)src;
    } else {
      int r   = rb * 16 + (ln & 15);
      int col = (kt - 8) * 64 + ks * 32 + (ln >> 4) * 8;
      v = load8<T>(h0 + ((size_t)((ped * 2 + 1) * 256 + bbase + r)) * 512 + col);
    }
    *(bf16x8*)(lds + (size_t)idx * 16) = v;
  }
  __syncthreads();   // the only barrier; LDS is read-only below

  const int whalf = wid & 1;         // 16-col half within a 32-col image tile
  const int wpair = wid >> 1;        // which 32-col tile of the 64-col hb group

  // W fragment loader: fills dst[g*2+ks] for this wave's 16 h-cols at (hb,kt)
  auto loadW = [&](bf16x8* dst, int hb, int kt) {
    const char* wim;
    int ktp;
    if (LAYER == 0)      { wim = ws + WS_W0;  ktp = kt; }
    else if (kt < 8)     { wim = ws + WS_W1A; ktp = kt; }
    else                 { wim = ws + WS_W1B; ktp = kt - 8; }
    const char* tile = wim + ((size_t)((hb * 2 + wpair) * 8 + ktp)) * TILE_BYTES;
#pragma unroll
    for (int g = 0; g < 4; ++g)
#pragma unroll
      for (int ks = 0; ks < 2; ++ks)
        dst[g * 2 + ks] = *(const bf16x8*)(tile + (((g * 2 + whalf) * 2 + ks) * 1024) + lane * 16);
  };

  const int crow0 = (ped * 2 + LAYER) * 256;

  for (int hb = 0; hb < 8; ++hb) {
    floatx4 acc[4][4];
#pragma unroll
    for (int g = 0; g < 4; ++g)
#pragma unroll
      for (int mi = 0; mi < 4; ++mi)
#pragma unroll
        for (int q = 0; q < 4; ++q) acc[g][mi][q] = 0.0f;

    bf16x8 wb[2][8];                 // register double-buffer (static indices)
    loadW(wb[0], hb, 0);

#pragma unroll
    for (int kt = 0; kt < KITERS; ++kt) {
      if (kt + 1 < KITERS) loadW(wb[(kt + 1) & 1], hb, kt + 1);  // in flight during MFMAs
      bf16x8 aF[8];
#pragma unroll
      for (int mi = 0; mi < 4; ++mi)
#pragma unroll
        for (int ks = 0; ks < 2; ++ks)
          aF[mi * 2 + ks] = *(const bf16x8*)(lds + (((kt * 4 + mi) * 2 + ks) * 1024) + lane * 16);
#pragma unroll
      for (int ks = 0; ks < 2; ++ks)
#pragma unroll
        for (int g = 0; g < 4; ++g)
#pragma unroll
          for (int mi = 0; mi < 4; ++mi)
            acc[g][mi] = __builtin_amdgcn_mfma_f32_16x16x32_bf16(
                aF[mi * 2 + ks], wb[kt & 1][g * 2 + ks], acc[g][mi], 0, 0, 0);
    }

    // ---- per-hb epilogue: bias + K=2 input GEMM (L0) + LSTM cell + stores ----
    const int hloc = hb * 64 + wpair * 32 + whalf * 16 + lrow;
    float bias[4], wx0[4], wx1[4];
#pragma unroll
    for (int g = 0; g < 4; ++g) {
      int j = g * 512 + hloc;
      bias[g] = tofl<T>(bih[j]) + tofl<T>(bhh[j]);
      if (LAYER == 0) {
        wx0[g] = tofl<T>(wih[j * 2]);
        wx1[g] = tofl<T>(wih[j * 2 + 1]);
      }
    }
    // A1A image coords for this h column (layer 0 handoff)
    const int kt_h = hloc >> 6;
    const int ks_h = (hloc >> 5) & 1;
    const int qd_h = (hloc >> 3) & 3;
    const int el_h = hloc & 7;
    char* a1a_tile = ws + WS_A1A + ((size_t)(pb * 8 + kt_h)) * TILE_BYTES;

#pragma unroll
    for (int mi = 0; mi < 4; ++mi) {
#pragma unroll
      for (int r = 0; r < 4; ++r) {
        int rr = mi * 16 + quad * 4 + r;      // row within the 64-row block
        int b  = bbase + rr;
        float gv0 = acc[0][mi][r] + bias[0];
        float gv1 = acc[1][mi][r] + bias[1];
        float gv2 = acc[2][mi][r] + bias[2];
        float gv3 = acc[3][mi][r] + bias[3];
        if (LAYER == 0) {
          float x0 = tofl<T>(xin[(b * 64 + ped) * 2]);
          float x1 = tofl<T>(xin[(b * 64 + ped) * 2 + 1]);
          gv0 += x0 * wx0[0] + x1 * wx1[0];
          gv1 += x0 * wx0[1] + x1 * wx1[1];
          gv2 += x0 * wx0[2] + x1 * wx1[2];
          gv3 += x0 * wx0[3] + x1 * wx1[3];
        }
        float ig = sigf(gv0), fg = sigf(gv1);
        float gg = tanh_(gv2), og = sigf(gv3);
        size_t ro = ((size_t)(crow0 + b)) * 512 + hloc;
        float co   = tofl<T>(c0[ro]);
        float cnew = fg * co + ig * gg;
        float hnew = og * tanh_(cnew);
        out[HN_BASE + ro] = fromfl<T>(hnew);
        out[CN_BASE + ro] = fromfl<T>(cnew);
        if (LAYER == 0) {
          int rri  = rrb + rr;                // row within the 128-row image tile
          int slot = (((rri >> 4) * 2 + ks_h) * 64) + qd_h * 16 + (rri & 15);
          *(short*)(a1a_tile + (size_t)slot * 16 + el_h * 2) = f2bf(hnew);
        }
        if (LAYER == 1)
          out[(size_t)(b * 64 + ped) * 512 + hloc] = fromfl<T>(hnew);
      }
    }
  }
}

template <int LAYER>
__global__ void __launch_bounds__(256, 2)
lstm_panel(const void* xin, const void* h0, const void* c0, const void* wih,
           const void* bih, const void* bhh, const void* det,
           void* out, void* ws)
{
  constexpr int KITERS = (LAYER == 0) ? 8 : 16;
  __shared__ __align__(16) char lds[KITERS * 8192];   // 64 KB (L0) / 128 KB (L1)
  if (detect_f32(det)) {
    lstm_panel_body<float, LAYER>((const float*)xin, (const float*)h0, (const float*)c0,
                                  (const float*)wih, (const float*)bih, (const float*)bhh,
                                  (float*)out, (char*)ws, lds);
  } else {
    lstm_panel_body<__hip_bfloat16, LAYER>((const __hip_bfloat16*)xin, (const __hip_bfloat16*)h0,
                                           (const __hip_bfloat16*)c0, (const __hip_bfloat16*)wih,
                                           (const __hip_bfloat16*)bih, (const __hip_bfloat16*)bhh,
                                           (__hip_bfloat16*)out, (char*)ws, lds);
  }
}

// ============================================================================
// Fallback (original verified kernel) — used if workspace is too small/absent.
// ============================================================================
template <typename T, int LAYER>
__device__ __forceinline__ void lstm_body(
    const T* __restrict__ xin, const T* __restrict__ h0, const T* __restrict__ c0,
    const T* __restrict__ wih, const T* __restrict__ whh,
    const T* __restrict__ bih, const T* __restrict__ bhh,
    T* out, __hip_bfloat16* ldsA, __hip_bfloat16* ldsW)
{
  const int tid  = threadIdx.x;
  const int nb   = blockIdx.x;
  const int hb   = blockIdx.y;
  const int lane = tid & 63;
  const int wid  = tid >> 6;
  const int quad = lane >> 4;
  const int lrow = lane & 15;
  const int p0   = nb >> 1;

  floatx4 acc[4][4];
#pragma unroll
  for (int g = 0; g < 4; ++g)
#pragma unroll
    for (int mi = 0; mi < 4; ++mi)
#pragma unroll
      for (int q = 0; q < 4; ++q) acc[g][mi][q] = 0.0f;

  int arow[4], wrow[4];
#pragma unroll
  for (int mi = 0; mi < 4; ++mi) arow[mi] = (wid >> 1) * 64 + mi * 16 + lrow;
#pragma unroll
  for (int g = 0; g < 4; ++g) wrow[g] = g * 32 + (wid & 1) * 16 + lrow;

  const int sr = tid >> 3;
  const int sc = tid & 7;
  const int KITERS = (LAYER == 0) ? 8 : 16;

  for (int kt = 0; kt < KITERS; ++kt) {
    bf16x8 ra[4], rw[4];
#pragma unroll
    for (int round = 0; round < 4; ++round) {
      int r = sr + round * 32;
      int b = ((nb & 1) << 7) + r;
      const T* srcA;
      if (LAYER == 0) {
        srcA = h0 + ((size_t)((p0 * 2) * 256 + b)) * 512 + kt * 64 + sc * 8;
      } else {
        if (kt < 8)
          srcA = out + HN_BASE + ((size_t)((p0 * 2) * 256 + b)) * 512 + kt * 64 + sc * 8;
        else
          srcA = h0 + ((size_t)((p0 * 2 + 1) * 256 + b)) * 512 + (kt - 8) * 64 + sc * 8;
      }
      ra[round] = load8<T>(srcA);

      int j = (r >> 5) * 512 + hb * 32 + (r & 31);
      const T* srcW;
      if (LAYER == 0) {
        srcW = whh + (size_t)j * 512 + kt * 64 + sc * 8;
      } else {
        if (kt < 8) srcW = wih + (size_t)j * 512 + kt * 64 + sc * 8;
        else        srcW = whh + (size_t)j * 512 + (kt - 8) * 64 + sc * 8;
      }
      rw[round] = load8<T>(srcW);
    }

    __syncthreads();
#pragma unroll
    for (int round = 0; round < 4; ++round) {
      int r = sr + round * 32;
      int p = sc ^ (r & 7);
      *(bf16x8*)((char*)ldsA + r * 128 + p * 16) = ra[round];
      *(bf16x8*)((char*)ldsW + r * 128 + p * 16) = rw[round];
    }
    __syncthreads();

#pragma unroll
    for (int ks = 0; ks < 2; ++ks) {
      bf16x8 aF[4], wF[4];
#pragma unroll
      for (int mi = 0; mi < 4; ++mi) {
        int ch = (ks * 4 + quad) ^ (arow[mi] & 7);
        aF[mi] = *(const bf16x8*)((const char*)ldsA + arow[mi] * 128 + ch * 16);
      }
#pragma unroll
      for (int g = 0; g < 4; ++g) {
        int ch = (ks * 4 + quad) ^ (wrow[g] & 7);
        wF[g] = *(const bf16x8*)((const char*)ldsW + wrow[g] * 128 + ch * 16);
      }
#pragma unroll
      for (int g = 0; g < 4; ++g)
#pragma unroll
        for (int mi = 0; mi < 4; ++mi)
          acc[g][mi] = __builtin_amdgcn_mfma_f32_16x16x32_bf16(
              aF[mi], wF[g], acc[g][mi], 0, 0, 0);
    }
  }

  const int hloc = hb * 32 + (wid & 1) * 16 + lrow;
  float bias[4], wx0[4], wx1[4];
#pragma unroll
  for (int g = 0; g < 4; ++g) {
    int j = g * 512 + hloc;
    bias[g] = tofl<T>(bih[j]) + tofl<T>(bhh[j]);
    if (LAYER == 0) {
      wx0[g] = tofl<T>(wih[j * 2]);
      wx1[g] = tofl<T>(wih[j * 2 + 1]);
    }
  }
  const int crow0 = (p0 * 2 + LAYER) * 256;
#pragma unroll
  for (int mi = 0; mi < 4; ++mi) {
#pragma unroll
    for (int r = 0; r < 4; ++r) {
      int b = ((nb & 1) << 7) + (wid >> 1) * 64 + mi * 16 + quad * 4 + r;
      float gv0 = acc[0][mi][r] + bias[0];
      float gv1 = acc[1][mi][r] + bias[1];
      float gv2 = acc[2][mi][r] + bias[2];
      float gv3 = acc[3][mi][r] + bias[3];
      if (LAYER == 0) {
        float x0 = tofl<T>(xin[(b * 64 + p0) * 2]);
        float x1 = tofl<T>(xin[(b * 64 + p0) * 2 + 1]);
        gv0 += x0 * wx0[0] + x1 * wx1[0];
        gv1 += x0 * wx0[1] + x1 * wx1[1];
        gv2 += x0 * wx0[2] + x1 * wx1[2];
        gv3 += x0 * wx0[3] + x1 * wx1[3];
      }
      float ig = sigf(gv0), fg = sigf(gv1);
      float gg = tanh_(gv2), og = sigf(gv3);
      size_t ro = ((size_t)(crow0 + b)) * 512 + hloc;
      float co   = tofl<T>(c0[ro]);
      float cnew = fg * co + ig * gg;
      float hnew = og * tanh_(cnew);
      out[HN_BASE + ro] = fromfl<T>(hnew);
      out[CN_BASE + ro] = fromfl<T>(cnew);
      if (LAYER == 1)
        out[(size_t)(b * 64 + p0) * 512 + hloc] = fromfl<T>(hnew);
    }
  }
}

template <int LAYER>
__global__ void __launch_bounds__(256)
lstm_layer(const void* xin, const void* h0, const void* c0,
           const void* wih, const void* whh, const void* bih, const void* bhh,
           const void* w_ih0_detect, void* out)
{
  __shared__ __align__(16) __hip_bfloat16 ldsA[128 * 64];
  __shared__ __align__(16) __hip_bfloat16 ldsW[128 * 64];
  if (detect_f32(w_ih0_detect)) {
    lstm_body<float, LAYER>((const float*)xin, (const float*)h0, (const float*)c0,
                            (const float*)wih, (const float*)whh,
                            (const float*)bih, (const float*)bhh,
                            (float*)out, ldsA, ldsW);
  } else {
    lstm_body<__hip_bfloat16, LAYER>((const __hip_bfloat16*)xin, (const __hip_bfloat16*)h0,
                                     (const __hip_bfloat16*)c0, (const __hip_bfloat16*)wih,
                                     (const __hip_bfloat16*)whh, (const __hip_bfloat16*)bih,
                                     (const __hip_bfloat16*)bhh, (__hip_bfloat16*)out,
                                     ldsA, ldsW);
  }
}

extern "C" void kernel_launch(void* const* d_in, const int* in_sizes, int n_in,
                              void* d_out, int out_size, void* d_ws, size_t ws_size,
                              hipStream_t stream) {
  dim3 block(256);
  if (d_ws != nullptr && ws_size >= WS_NEED) {
    // tiny pre-pass: fragment-order bf16 W images (whh0, wih1, whh1)
    prep_W_k<<<dim3(48, 8), block, 0, stream>>>(d_in[4], d_in[7], d_in[8], d_in[3], d_ws);
    dim3 grid(256);   // 64 rows x 512 h per block
    lstm_panel<0><<<grid, block, 0, stream>>>(d_in[0], d_in[1], d_in[2], d_in[3],
                                              d_in[5], d_in[6], d_in[3], d_out, d_ws);
    lstm_panel<1><<<grid, block, 0, stream>>>(d_in[0], d_in[1], d_in[2], d_in[3],
                                              d_in[9], d_in[10], d_in[3], d_out, d_ws);
  } else {
    dim3 grid(MM / 128, HH / 32);
    lstm_layer<0><<<grid, block, 0, stream>>>(d_in[0], d_in[1], d_in[2],
                                              d_in[3], d_in[4], d_in[5], d_in[6],
                                              d_in[3], d_out);
    lstm_layer<1><<<grid, block, 0, stream>>>(d_in[0], d_in[1], d_in[2],
                                              d_in[7], d_in[8], d_in[9], d_in[10],
                                              d_in[3], d_out);
  }
}

// Round 8
// 457.695 us; speedup vs baseline: 2.2970x; 2.2970x over previous
//
#include <hip/hip_runtime.h>
#include <hip/hip_bf16.h>

// Problem constants
#define PP 64
#define BB 256
#define HH 512
#define MM (PP * BB)          // 16384 fused batch rows

// d_out layout: out (B,P,H) | hn (P,2,B,H) | cn (P,2,B,H)
#define HN_BASE (BB * PP * HH)                 // 8388608
#define CN_BASE (HN_BASE + PP * 2 * BB * HH)   // 25165824

// ---- workspace layout (bytes): FRAGMENT-ORDER bf16 tile images, BK=32 ----
// 8 KB tile = 512 slots of 16B, slot = rb*64 + lane (lane = qd*16 + lr):
//   A tiles [pb 0..127][kt32]: lane holds A[rb*16+lr][kt32*32 + qd*8 ..+8]
//   W tiles [hb 0..15][kt32]:  rb=g*2+half -> W row g*512+hb*32+half*16+lr
// Staging a tile is a verbatim byte-copy (DMA: wave-uniform dest + lane*16);
// LDS fragment reads are contiguous lane-major ds_read_b128 (conflict-free).
#define TILE8K 8192
#define WS_A0   0ull                          // h0[:,0]  image    16 MiB  (16 kt32)
#define WS_A1A  16777216ull                   // h_new0   image    16 MiB  (16 kt32)
#define WS_A1B  33554432ull                   // h0[:,1]  image    16 MiB  (16 kt32)
#define WS_W0   50331648ull                   // whh0  image   2 MiB (16 hb x 16 kt32)
#define WS_W1A  52428800ull                   // wih1  image   2 MiB
#define WS_W1B  54525952ull                   // whh1  image   2 MiB
#define WS_NEED 56623104ull

typedef __attribute__((ext_vector_type(8))) short bf16x8;
typedef __attribute__((ext_vector_type(4))) float floatx4;

__device__ __forceinline__ float sigf(float x) { return 1.0f / (1.0f + __expf(-x)); }
__device__ __forceinline__ float tanh_(float x) { return 2.0f / (1.0f + __expf(-2.0f * x)) - 1.0f; }

// float -> bf16 bits, round-nearest-even (finite inputs only)
__device__ __forceinline__ short f2bf(float f) {
  unsigned u = __float_as_uint(f);
  u = (u + 0x7FFFu + ((u >> 16) & 1u)) >> 16;
  return (short)u;
}

template <typename T>
__device__ __forceinline__ float tofl(T v);
template <> __device__ __forceinline__ float tofl<float>(float v) { return v; }
template <> __device__ __forceinline__ float tofl<__hip_bfloat16>(__hip_bfloat16 v) { return __bfloat162float(v); }

template <typename T>
__device__ __forceinline__ T fromfl(float v);
template <> __device__ __forceinline__ float fromfl<float>(float v) { return v; }
template <> __device__ __forceinline__ __hip_bfloat16 fromfl<__hip_bfloat16>(float v) { return __float2bfloat16(v); }

// load 8 consecutive elements as bf16x8 (16B-aligned for bf16, 32B for f32)
template <typename T>
__device__ __forceinline__ bf16x8 load8(const T* p);
template <> __device__ __forceinline__ bf16x8 load8<__hip_bfloat16>(const __hip_bfloat16* p) {
  return *(const bf16x8*)p;
}
template <> __device__ __forceinline__ bf16x8 load8<float>(const float* p) {
  float4 f0 = *(const float4*)p;
  float4 f1 = *((const float4*)p + 1);
  bf16x8 v;
  v[0] = f2bf(f0.x); v[1] = f2bf(f0.y); v[2] = f2bf(f0.z); v[3] = f2bf(f0.w);
  v[4] = f2bf(f1.x); v[5] = f2bf(f1.y); v[6] = f2bf(f1.z); v[7] = f2bf(f1.w);
  return v;
}

// fp32 vs bf16 buffer detection (see original kernel comment)
__device__ __forceinline__ bool detect_f32(const void* w_ih0) {
  const unsigned short* p = (const unsigned short*)w_ih0;
  int l = threadIdx.x & 63;
  unsigned short a = p[2 * l], b = p[2 * l + 1];
  int big = ((a & 0x7F80) >= 0x3F80) || ((b & 0x7F80) >= 0x3F80);
  return __any(big);
}

// async global -> LDS, 16 bytes per lane. LDS dest is wave-uniform + lane*16.
__device__ __forceinline__ void gload16(void* ldsp, const void* g) {
  __builtin_amdgcn_global_load_lds(
      (const __attribute__((address_space(1))) unsigned int*)g,
      (__attribute__((address_space(3))) unsigned int*)ldsp, 16, 0, 0);
}

// ============================================================================
// Pre-pass: fragment-order bf16 tile images (BK=32)
// ============================================================================

// A tiles from h0 (P,L,B,H). grid (128 pb, 16 kt32, 2 l), block 256.
template <typename T>
__device__ __forceinline__ void prep_A_body(const T* __restrict__ h0, char* __restrict__ ws) {
  const int pb = blockIdx.x, kt = blockIdx.y, l = blockIdx.z;
  char* dst = ws + (l ? WS_A1B : WS_A0) + ((size_t)(pb * 16 + kt)) * TILE8K;
  const int ped = pb >> 1, bh = pb & 1;
  const T* src = h0 + ((size_t)(ped * 2 + l) * 256) * 512;
  const int tid = threadIdx.x;
#pragma unroll
  for (int i = 0; i < 2; ++i) {
    int idx = i * 256 + tid;          // slot 0..511
    int ln  = idx & 63;
    int rb  = idx >> 6;               // 0..7
    int row = bh * 128 + rb * 16 + (ln & 15);
    int col = kt * 32 + (ln >> 4) * 8;
    *(bf16x8*)(dst + (size_t)idx * 16) = load8<T>(src + (size_t)row * 512 + col);
  }
}

__global__ void __launch_bounds__(256) prep_A_k(const void* h0, const void* det, void* ws) {
  if (detect_f32(det)) prep_A_body<float>((const float*)h0, (char*)ws);
  else prep_A_body<__hip_bfloat16>((const __hip_bfloat16*)h0, (char*)ws);
}

// W tiles from the three [2048,512] matrices. grid (48 = 3*16, 16 kt32), block 256.
template <typename T>
__device__ __forceinline__ void prep_W_body(const T* __restrict__ w0, const T* __restrict__ w1a,
                                            const T* __restrict__ w1b, char* __restrict__ ws) {
  const int m = blockIdx.x >> 4, hb = blockIdx.x & 15, kt = blockIdx.y;
  const T* src = (m == 0) ? w0 : (m == 1 ? w1a : w1b);
  const size_t base = (m == 0) ? WS_W0 : (m == 1 ? WS_W1A : WS_W1B);
  char* dst = ws + base + ((size_t)(hb * 16 + kt)) * TILE8K;
  const int tid = threadIdx.x;
#pragma unroll
  for (int i = 0; i < 2; ++i) {
    int idx = i * 256 + tid;
    int ln  = idx & 63;
    int rb  = idx >> 6;               // rb = g*2 + half
    int g   = rb >> 1, half = rb & 1;
    int j   = g * 512 + hb * 32 + half * 16 + (ln & 15);   // row in [2048,512]
    int col = kt * 32 + (ln >> 4) * 8;
    *(bf16x8*)(dst + (size_t)idx * 16) = load8<T>(src + (size_t)j * 512 + col);
  }
}

__global__ void __launch_bounds__(256) prep_W_k(const void* w0, const void* w1a, const void* w1b,
                                                const void* det, void* ws) {
  if (detect_f32(det)) prep_W_body<float>((const float*)w0, (const float*)w1a, (const float*)w1b, (char*)ws);
  else prep_W_body<__hip_bfloat16>((const __hip_bfloat16*)w0, (const __hip_bfloat16*)w1a,
                                   (const __hip_bfloat16*)w1b, (char*)ws);
}

// ============================================================================
// Main layer kernel (R5 structure, BK=32): DMA staging into double-buffered
// 32 KB LDS (4 blocks/CU), prefetch of kt+1 issued before kt's MFMAs, plain
// __syncthreads() per iteration (implicit vmcnt(0) drain — hidden by TLP).
// grid (hb=16, nb=128): consecutive blocks share the A tile (L2 locality).
// ============================================================================
template <typename T, int LAYER>
__device__ __forceinline__ void lstm_dma_body(
    const T* __restrict__ xin, const T* __restrict__ c0,
    const T* __restrict__ wih, const T* __restrict__ bih, const T* __restrict__ bhh,
    T* __restrict__ out, char* __restrict__ ws, char* lds)
{
  const int tid  = threadIdx.x;
  const int hb   = blockIdx.x;   // h-block 0..15 (fast: A-tile sharing)
  const int nb   = blockIdx.y;   // n-block 0..127 (== pb of A tiles)
  const int lane = tid & 63;
  const int wid  = tid >> 6;
  const int quad = lane >> 4;
  const int lrow = lane & 15;
  const int p0   = nb >> 1;

  floatx4 acc[4][4];             // [gate][mi]
#pragma unroll
  for (int g = 0; g < 4; ++g)
#pragma unroll
    for (int mi = 0; mi < 4; ++mi)
#pragma unroll
      for (int q = 0; q < 4; ++q) acc[g][mi][q] = 0.0f;

  const int a_rb0  = (wid >> 1) * 4;   // first A row-block for this wave
  const int w_half = wid & 1;

  constexpr int KITERS = (LAYER == 0) ? 16 : 32;   // K = 512 or 1024, BK=32

  auto stage = [&](int buf, int kt) {
    const char *at, *wt;
    if (LAYER == 0) {
      at = ws + WS_A0  + ((size_t)(nb * 16 + kt)) * TILE8K;
      wt = ws + WS_W0  + ((size_t)(hb * 16 + kt)) * TILE8K;
    } else if (kt < 16) {
      at = ws + WS_A1A + ((size_t)(nb * 16 + kt)) * TILE8K;
      wt = ws + WS_W1A + ((size_t)(hb * 16 + kt)) * TILE8K;
    } else {
      at = ws + WS_A1B + ((size_t)(nb * 16 + kt - 16)) * TILE8K;
      wt = ws + WS_W1B + ((size_t)(hb * 16 + kt - 16)) * TILE8K;
    }
    char* la = lds + buf * 16384;
    char* lw = la + TILE8K;
#pragma unroll
    for (int i = 0; i < 2; ++i) {
      int base = (i * 4 + wid) * 1024;       // wave-uniform LDS dest (verbatim copy)
      int off  = base + lane * 16;           // per-lane global source
      gload16(la + base, at + off);          // 4 VMEM ops per thread per stage
      gload16(lw + base, wt + off);
    }
  };

  // prologue: fill buffer 0 (syncthreads' implicit vmcnt(0) drains the DMA)
  stage(0, 0);
  __syncthreads();

#pragma unroll
  for (int kt = 0; kt < KITERS; ++kt) {
    const int cur = kt & 1;
    if (kt + 1 < KITERS) stage(cur ^ 1, kt + 1);   // DMA in flight during MFMAs

    const char* la = lds + cur * 16384;
    const char* lw = la + TILE8K;
    bf16x8 aF[4], wF[4];
#pragma unroll
    for (int mi = 0; mi < 4; ++mi)
      aF[mi] = *(const bf16x8*)(la + ((a_rb0 + mi) * 1024) + lane * 16);
#pragma unroll
    for (int g = 0; g < 4; ++g)
      wF[g] = *(const bf16x8*)(lw + ((g * 2 + w_half) * 1024) + lane * 16);
#pragma unroll
    for (int g = 0; g < 4; ++g)
#pragma unroll
      for (int mi = 0; mi < 4; ++mi)
        acc[g][mi] = __builtin_amdgcn_mfma_f32_16x16x32_bf16(
            aF[mi], wF[g], acc[g][mi], 0, 0, 0);

    // barrier: (a) all waves done reading buf cur -> safe to overwrite next
    // iter; (b) implicit vmcnt(0) drain -> buf cur^1 DMA complete.
    __syncthreads();
  }

  // --- epilogue: biases + K=2 input GEMM (L0) + LSTM cell + stores ---
  const int hloc = hb * 32 + w_half * 16 + lrow;   // global h (C/D col = lane&15)
  float bias[4], wx0[4], wx1[4];
#pragma unroll
  for (int g = 0; g < 4; ++g) {
    int j = g * 512 + hloc;
    bias[g] = tofl<T>(bih[j]) + tofl<T>(bhh[j]);
    if (LAYER == 0) {
      wx0[g] = tofl<T>(wih[j * 2]);
      wx1[g] = tofl<T>(wih[j * 2 + 1]);
    }
  }
  const int crow0 = (p0 * 2 + LAYER) * 256;
  // A1A fragment-image coordinates for this thread's h column (layer 0 only)
  const int kt_h = hloc >> 5;          // kt32 of this h column
  const int qd_h = (hloc >> 3) & 3;
  const int el_h = hloc & 7;
  char* a1a_tile = ws + WS_A1A + ((size_t)(nb * 16 + kt_h)) * TILE8K;

#pragma unroll
  for (int mi = 0; mi < 4; ++mi) {
#pragma unroll
    for (int r = 0; r < 4; ++r) {
      // C/D layout: row(m=batch) = quad*4 + r, col(n=h) = lane&15
      int rr = (wid >> 1) * 64 + mi * 16 + quad * 4 + r;   // row within 128-row tile
      int b  = ((nb & 1) << 7) + rr;
      float gv0 = acc[0][mi][r] + bias[0];
      float gv1 = acc[1][mi][r] + bias[1];
      float gv2 = acc[2][mi][r] + bias[2];
      float gv3 = acc[3][mi][r] + bias[3];
      if (LAYER == 0) {
        float x0 = tofl<T>(xin[(b * 64 + p0) * 2]);
        float x1 = tofl<T>(xin[(b * 64 + p0) * 2 + 1]);
        gv0 += x0 * wx0[0] + x1 * wx1[0];
        gv1 += x0 * wx0[1] + x1 * wx1[1];
        gv2 += x0 * wx0[2] + x1 * wx1[2];
        gv3 += x0 * wx0[3] + x1 * wx1[3];
      }
      float ig = sigf(gv0), fg = sigf(gv1);
      float gg = tanh_(gv2), og = sigf(gv3);
      size_t ro = ((size_t)(crow0 + b)) * 512 + hloc;
      float co   = tofl<T>(c0[ro]);
      float cnew = fg * co + ig * gg;
      float hnew = og * tanh_(cnew);
      out[HN_BASE + ro] = fromfl<T>(hnew);
      out[CN_BASE + ro] = fromfl<T>(cnew);
      if (LAYER == 0) {
        // bf16 copy into layer-1's A fragment image (8 KB tiles):
        // slot = (rr>>4)*64 + qd*16 + (rr&15), element el within slot
        int slot = ((rr >> 4) * 64) + qd_h * 16 + (rr & 15);
        *(short*)(a1a_tile + (size_t)slot * 16 + el_h * 2) = f2bf(hnew);
      }
      if (LAYER == 1)
        out[(size_t)(b * 64 + p0) * 512 + hloc] = fromfl<T>(hnew);
    }
  }
}

template <int LAYER>
__global__ void __launch_bounds__(256, 4)
lstm_dma(const void* xin, const void* c0, const void* wih,
         const void* bih, const void* bhh, const void* det,
         void* out, void* ws)
{
  __shared__ __align__(16) char lds[2 * 16384];   // dbuf x (A 8K + W 8K) = 32 KB
  if (detect_f32(det)) {
    lstm_dma_body<float, LAYER>((const float*)xin, (const float*)c0, (const float*)wih,
                                (const float*)bih, (const float*)bhh,
                                (float*)out, (char*)ws, lds);
  } else {
    lstm_dma_body<__hip_bfloat16, LAYER>((const __hip_bfloat16*)xin, (const __hip_bfloat16*)c0,
                                         (const __hip_bfloat16*)wih, (const __hip_bfloat16*)bih,
                                         (const __hip_bfloat16*)bhh,
                                         (__hip_bfloat16*)out, (char*)ws, lds);
  }
}

// ============================================================================
// Fallback (original verified kernel) — used if workspace is too small/absent.
// ============================================================================
template <typename T, int LAYER>
__device__ __forceinline__ void lstm_body(
    const T* __restrict__ xin, const T* __restrict__ h0, const T* __restrict__ c0,
    const T* __restrict__ wih, const T* __restrict__ whh,
    const T* __restrict__ bih, const T* __restrict__ bhh,
    T* out, __hip_bfloat16* ldsA, __hip_bfloat16* ldsW)
{
  const int tid  = threadIdx.x;
  const int nb   = blockIdx.x;
  const int hb   = blockIdx.y;
  const int lane = tid & 63;
  const int wid  = tid >> 6;
  const int quad = lane >> 4;
  const int lrow = lane & 15;
  const int p0   = nb >> 1;

  floatx4 acc[4][4];
#pragma unroll
  for (int g = 0; g < 4; ++g)
#pragma unroll
    for (int mi = 0; mi < 4; ++mi)
#pragma unroll
      for (int q = 0; q < 4; ++q) acc[g][mi][q] = 0.0f;

  int arow[4], wrow[4];
#pragma unroll
  for (int mi = 0; mi < 4; ++mi) arow[mi] = (wid >> 1) * 64 + mi * 16 + lrow;
#pragma unroll
  for (int g = 0; g < 4; ++g) wrow[g] = g * 32 + (wid & 1) * 16 + lrow;

  const int sr = tid >> 3;
  const int sc = tid & 7;
  const int KITERS = (LAYER == 0) ? 8 : 16;

  for (int kt = 0; kt < KITERS; ++kt) {
    bf16x8 ra[4], rw[4];
#pragma unroll
    for (int round = 0; round < 4; ++round) {
      int r = sr + round * 32;
      int b = ((nb & 1) << 7) + r;
      const T* srcA;
      if (LAYER == 0) {
        srcA = h0 + ((size_t)((p0 * 2) * 256 + b)) * 512 + kt * 64 + sc * 8;
      } else {
        if (kt < 8)
          srcA = out + HN_BASE + ((size_t)((p0 * 2) * 256 + b)) * 512 + kt * 64 + sc * 8;
        else
          srcA = h0 + ((size_t)((p0 * 2 + 1) * 256 + b)) * 512 + (kt - 8) * 64 + sc * 8;
      }
      ra[round] = load8<T>(srcA);

      int j = (r >> 5) * 512 + hb * 32 + (r & 31);
      const T* srcW;
      if (LAYER == 0) {
        srcW = whh + (size_t)j * 512 + kt * 64 + sc * 8;
      } else {
        if (kt < 8) srcW = wih + (size_t)j * 512 + kt * 64 + sc * 8;
        else        srcW = whh + (size_t)j * 512 + (kt - 8) * 64 + sc * 8;
      }
      rw[round] = load8<T>(srcW);
    }

    __syncthreads();
#pragma unroll
    for (int round = 0; round < 4; ++round) {
      int r = sr + round * 32;
      int p = sc ^ (r & 7);
      *(bf16x8*)((char*)ldsA + r * 128 + p * 16) = ra[round];
      *(bf16x8*)((char*)ldsW + r * 128 + p * 16) = rw[round];
    }
    __syncthreads();

#pragma unroll
    for (int ks = 0; ks < 2; ++ks) {
      bf16x8 aF[4], wF[4];
#pragma unroll
      for (int mi = 0; mi < 4; ++mi) {
        int ch = (ks * 4 + quad) ^ (arow[mi] & 7);
        aF[mi] = *(const bf16x8*)((const char*)ldsA + arow[mi] * 128 + ch * 16);
      }
#pragma unroll
      for (int g = 0; g < 4; ++g) {
        int ch = (ks * 4 + quad) ^ (wrow[g] & 7);
        wF[g] = *(const bf16x8*)((const char*)ldsW + wrow[g] * 128 + ch * 16);
      }
#pragma unroll
      for (int g = 0; g < 4; ++g)
#pragma unroll
        for (int mi = 0; mi < 4; ++mi)
          acc[g][mi] = __builtin_amdgcn_mfma_f32_16x16x32_bf16(
              aF[mi], wF[g], acc[g][mi], 0, 0, 0);
    }
  }

  const int hloc = hb * 32 + (wid & 1) * 16 + lrow;
  float bias[4], wx0[4], wx1[4];
#pragma unroll
  for (int g = 0; g < 4; ++g) {
    int j = g * 512 + hloc;
    bias[g] = tofl<T>(bih[j]) + tofl<T>(bhh[j]);
    if (LAYER == 0) {
      wx0[g] = tofl<T>(wih[j * 2]);
      wx1[g] = tofl<T>(wih[j * 2 + 1]);
    }
  }
  const int crow0 = (p0 * 2 + LAYER) * 256;
#pragma unroll
  for (int mi = 0; mi < 4; ++mi) {
#pragma unroll
    for (int r = 0; r < 4; ++r) {
      int b = ((nb & 1) << 7) + (wid >> 1) * 64 + mi * 16 + quad * 4 + r;
      float gv0 = acc[0][mi][r] + bias[0];
      float gv1 = acc[1][mi][r] + bias[1];
      float gv2 = acc[2][mi][r] + bias[2];
      float gv3 = acc[3][mi][r] + bias[3];
      if (LAYER == 0) {
        float x0 = tofl<T>(xin[(b * 64 + p0) * 2]);
        float x1 = tofl<T>(xin[(b * 64 + p0) * 2 + 1]);
        gv0 += x0 * wx0[0] + x1 * wx1[0];
        gv1 += x0 * wx0[1] + x1 * wx1[1];
        gv2 += x0 * wx0[2] + x1 * wx1[2];
        gv3 += x0 * wx0[3] + x1 * wx1[3];
      }
      float ig = sigf(gv0), fg = sigf(gv1);
      float gg = tanh_(gv2), og = sigf(gv3);
      size_t ro = ((size_t)(crow0 + b)) * 512 + hloc;
      float co   = tofl<T>(c0[ro]);
      float cnew = fg * co + ig * gg;
      float hnew = og * tanh_(cnew);
      out[HN_BASE + ro] = fromfl<T>(hnew);
      out[CN_BASE + ro] = fromfl<T>(cnew);
      if (LAYER == 1)
        out[(size_t)(b * 64 + p0) * 512 + hloc] = fromfl<T>(hnew);
    }
  }
}

template <int LAYER>
__global__ void __launch_bounds__(256)
lstm_layer(const void* xin, const void* h0, const void* c0,
           const void* wih, const void* whh, const void* bih, const void* bhh,
           const void* w_ih0_detect, void* out)
{
  __shared__ __align__(16) __hip_bfloat16 ldsA[128 * 64];
  __shared__ __align__(16) __hip_bfloat16 ldsW[128 * 64];
  if (detect_f32(w_ih0_detect)) {
    lstm_body<float, LAYER>((const float*)xin, (const float*)h0, (const float*)c0,
                            (const float*)wih, (const float*)whh,
                            (const float*)bih, (const float*)bhh,
                            (float*)out, ldsA, ldsW);
  } else {
    lstm_body<__hip_bfloat16, LAYER>((const __hip_bfloat16*)xin, (const __hip_bfloat16*)h0,
                                     (const __hip_bfloat16*)c0, (const __hip_bfloat16*)wih,
                                     (const __hip_bfloat16*)whh, (const __hip_bfloat16*)bih,
                                     (const __hip_bfloat16*)bhh, (__hip_bfloat16*)out,
                                     ldsA, ldsW);
  }
}

extern "C" void kernel_launch(void* const* d_in, const int* in_sizes, int n_in,
                              void* d_out, int out_size, void* d_ws, size_t ws_size,
                              hipStream_t stream) {
  dim3 block(256);
  if (d_ws != nullptr && ws_size >= WS_NEED) {
    // pre-pass: fragment-order bf16 tile images (BK=32)
    prep_A_k<<<dim3(128, 16, 2), block, 0, stream>>>(d_in[1], d_in[3], d_ws);
    prep_W_k<<<dim3(48, 16), block, 0, stream>>>(d_in[4], d_in[7], d_in[8], d_in[3], d_ws);
    dim3 grid(HH / 32, MM / 128);   // (16 hb, 128 nb): A-tile sharing blocks adjacent
    lstm_dma<0><<<grid, block, 0, stream>>>(d_in[0], d_in[2], d_in[3],
                                            d_in[5], d_in[6], d_in[3], d_out, d_ws);
    lstm_dma<1><<<grid, block, 0, stream>>>(d_in[0], d_in[2], d_in[3],
                                            d_in[9], d_in[10], d_in[3], d_out, d_ws);
  } else {
    dim3 grid(MM / 128, HH / 32);
    lstm_layer<0><<<grid, block, 0, stream>>>(d_in[0], d_in[1], d_in[2],
                                              d_in[3], d_in[4], d_in[5], d_in[6],
                                              d_in[3], d_out);
    lstm_layer<1><<<grid, block, 0, stream>>>(d_in[0], d_in[1], d_in[2],
                                              d_in[7], d_in[8], d_in[9], d_in[10],
                                              d_in[3], d_out);
  }
}